// Round 1
// baseline (681.925 us; speedup 1.0000x reference)
//
#include <hip/hip_runtime.h>
#include <math.h>

#define XP 960
typedef __attribute__((ext_vector_type(8))) short short8;
typedef __attribute__((ext_vector_type(4))) float f32x4;
typedef __attribute__((ext_vector_type(4))) float fv4;
typedef __attribute__((ext_vector_type(4))) unsigned uint4v;

// Packed bf16 weights in MFMA fragment order (serves as B-frag for X@W and
// identically as A-frag for W^T@X^T). Offsets in shorts:
//  w1s:0  w1v1:114688  w1v2:131072  w2s:135168  w2v1:200704  w2v2:217088
__device__ short g_pack[221184];

__device__ __forceinline__ short f2bf(float f) {
    union { float f; unsigned u; } v; v.f = f;
    unsigned r = (v.u + 0x7fffu + ((v.u >> 16) & 1u)) >> 16;
    return (short)r;
}
// pack two floats -> dword of 2 bf16 (round-to-nearest, half-up)
__device__ __forceinline__ unsigned pk2(float a, float b) {
    union { float f; unsigned u; } x, y; x.f = a; y.f = b;
    return ((x.u + 0x8000u) >> 16) | ((y.u + 0x8000u) & 0xffff0000u);
}
__device__ __forceinline__ short8 mk8(unsigned d0, unsigned d1, unsigned d2, unsigned d3) {
    union { uint4v u; short8 s; } cv;
    cv.u = (uint4v){d0, d1, d2, d3};
    return cv.s;
}
__device__ __forceinline__ float ssp(float v, float c) {
    // c * (softplus(v) - ln2), stable: max(v,0) + ln2*log2(1 + 2^(-|v|*log2e))
    float t = exp2f(fabsf(v) * -1.44269504088896340736f);
    float sp = fmaxf(v, 0.f) + 0.69314718055994530942f * __log2f(1.0f + t);
    return c * (sp - 0.69314718055994530942f);
}

#define WSYNC() asm volatile("s_waitcnt lgkmcnt(0)" ::: "memory")
#define MFMA(a, b, c) __builtin_amdgcn_mfma_f32_16x16x32_bf16((a), (b), (c), 0, 0, 0)
#define NTL(p) __builtin_nontemporal_load((const fv4*)(p))
#define NTS(p, v) __builtin_nontemporal_store((v), (fv4*)(p))

__global__ void pack_weights(const float* __restrict__ w1s, const float* __restrict__ w1v1,
                             const float* __restrict__ w1v2, const float* __restrict__ w2s,
                             const float* __restrict__ w2v1, const float* __restrict__ w2v2) {
    int g = blockIdx.x * blockDim.x + threadIdx.x;
    const float* src; int NT, N, dstoff, lg;
    if      (g < 14336) { src = w1s;  NT = 28; N = 448; dstoff = 0;      lg = g; }
    else if (g < 16384) { src = w1v1; NT = 8;  N = 128; dstoff = 114688; lg = g - 14336; }
    else if (g < 16896) { src = w1v2; NT = 4;  N = 64;  dstoff = 131072; lg = g - 16384; }
    else if (g < 25088) { src = w2s;  NT = 16; N = 256; dstoff = 135168; lg = g - 16896; }
    else if (g < 27136) { src = w2v1; NT = 8;  N = 128; dstoff = 200704; lg = g - 25088; }
    else if (g < 27648) { src = w2v2; NT = 4;  N = 64;  dstoff = 217088; lg = g - 27136; }
    else return;
    int lane = lg & 63;
    int t = lg >> 6;
    int nt = t % NT;
    int kt = t / NT;
    int k0 = kt * 32 + (lane >> 4) * 8;
    int n  = nt * 16 + (lane & 15);
    short* dst = g_pack + dstoff + (size_t)lg * 8;
#pragma unroll
    for (int j = 0; j < 8; j++) dst[j] = f2bf(src[(size_t)(k0 + j) * N + n]);
}

// 4 blocks/CU (LDS 33792/block), 1024-block grid = fully resident, no tail.
__global__ __launch_bounds__(256, 4) void fused_kernel(const float* __restrict__ x,
                                                       float* __restrict__ out,
                                                       float c_ssp) {
    // One per-wave arena; per-sample pitch 264 shorts (528 B, 16B-aligned).
    // The SAME slot [0..k) per sample is reused sequentially:
    //   scalars (256 sh) -> v1 channel c (136 sh, streamed one at a time)
    //   -> v2 channel c (72 sh, streamed one at a time).
    // Safety: per-wave DS ops execute in order; WSYNC ("memory" clobber +
    // lgkmcnt(0)) fences the compiler between write-group / read-group / reuse.
    __shared__ __align__(16) short arena[4][16 * 264];

    const int lane = threadIdx.x & 63;
    const int wave = threadIdx.x >> 6;
    const int q = lane >> 4, l15 = lane & 15;
    const int row0 = blockIdx.x * 64 + wave * 16;
    short* S = arena[wave];
    unsigned* Sd = (unsigned*)S;
    const int dwb = l15 * 132 + q * 2;        // dword base for C-layout pair-stores
    const short* Sr = S + l15 * 264 + q * 8;  // b128 read base (k = kt*32+q*8)

    const short8* pw1s  = (const short8*)(g_pack + 0);
    const short8* pw1v1 = (const short8*)(g_pack + 114688);
    const short8* pw1v2 = (const short8*)(g_pack + 131072);
    const short8* pw2s  = (const short8*)(g_pack + 135168);
    const short8* pw2v1 = (const short8*)(g_pack + 200704);
    const short8* pw2v2 = (const short8*)(g_pack + 217088);

    const float* xrow = x + (size_t)(row0 + l15) * XP;
    float* yrow = out + (size_t)(row0 + l15) * XP;

    const float S1  = 0.0625f;                // 1/sqrt(256)
    const float SV1 = 0.08838834764831845f;   // 1/sqrt(128)
    const float SV2 = 0.125f;                 // 1/sqrt(64)

    // ---- phase 0: x0 fragments (lane = own sample row; serves as B operand) ----
    short8 xf0[8];
#pragma unroll
    for (int kt = 0; kt < 8; kt++) {
        fv4 u0 = *(const fv4*)(xrow + kt * 32 + q * 8);
        fv4 u1 = *(const fv4*)(xrow + kt * 32 + q * 8 + 4);
        xf0[kt] = mk8(pk2(u0[0], u0[1]), pk2(u0[2], u0[3]), pk2(u1[0], u1[1]), pk2(u1[2], u1[3]));
    }

    // ---- phase 1: S^T = W1s^T X0^T ; scalars -> LDS (B-layout), gates -> regs ----
#pragma unroll 1
    for (int tp = 0; tp < 8; tp++) {          // scalar tiles t = 0..15
        f32x4 a0 = {0.f,0.f,0.f,0.f}, a1 = {0.f,0.f,0.f,0.f};
#pragma unroll
        for (int kt = 0; kt < 8; kt++) {
            a0 = MFMA(pw1s[(kt * 28 + 2 * tp + 0) * 64 + lane], xf0[kt], a0);
            a1 = MFMA(pw1s[(kt * 28 + 2 * tp + 1) * 64 + lane], xf0[kt], a1);
        }
#pragma unroll
        for (int h = 0; h < 2; h++) {
            f32x4 a = h ? a1 : a0;
            int t = 2 * tp + h;
            Sd[dwb + t * 8]     = pk2(ssp(a[0] * S1, c_ssp), ssp(a[1] * S1, c_ssp));
            Sd[dwb + t * 8 + 1] = pk2(ssp(a[2] * S1, c_ssp), ssp(a[3] * S1, c_ssp));
        }
    }
    f32x4 gacc[12];
#pragma unroll
    for (int tp = 0; tp < 6; tp++) {          // gate tiles t = 16..27 (static gacc idx)
        f32x4 a0 = {0.f,0.f,0.f,0.f}, a1 = {0.f,0.f,0.f,0.f};
#pragma unroll
        for (int kt = 0; kt < 8; kt++) {
            a0 = MFMA(pw1s[(kt * 28 + 16 + 2 * tp + 0) * 64 + lane], xf0[kt], a0);
            a1 = MFMA(pw1s[(kt * 28 + 16 + 2 * tp + 1) * 64 + lane], xf0[kt], a1);
        }
        gacc[2 * tp]     = (f32x4){ssp(a0[0]*S1,c_ssp), ssp(a0[1]*S1,c_ssp), ssp(a0[2]*S1,c_ssp), ssp(a0[3]*S1,c_ssp)};
        gacc[2 * tp + 1] = (f32x4){ssp(a1[0]*S1,c_ssp), ssp(a1[1]*S1,c_ssp), ssp(a1[2]*S1,c_ssp), ssp(a1[3]*S1,c_ssp)};
    }
    WSYNC();

    // ---- phase 2: Y0^T = W2s^T Scal^T ; epilogue = per-lane float4 on own row ----
    short8 sf[8];
#pragma unroll
    for (int kt = 0; kt < 8; kt++) sf[kt] = *(const short8*)(Sr + kt * 32);
    WSYNC();   // fence: scalar reads complete before v1 reuses the slot
#pragma unroll 1
    for (int tp = 0; tp < 8; tp++) {
        f32x4 a0 = {0.f,0.f,0.f,0.f}, a1 = {0.f,0.f,0.f,0.f};
#pragma unroll
        for (int kt = 0; kt < 8; kt++) {
            a0 = MFMA(pw2s[(kt * 16 + 2 * tp + 0) * 64 + lane], sf[kt], a0);
            a1 = MFMA(pw2s[(kt * 16 + 2 * tp + 1) * 64 + lane], sf[kt], a1);
        }
#pragma unroll
        for (int h = 0; h < 2; h++) {
            f32x4 a = h ? a1 : a0;
            int col = (2 * tp + h) * 16 + q * 4;
            fv4 r = NTL(xrow + col);
            fv4 o = {r[0] + a[0] * S1, r[1] + a[1] * S1, r[2] + a[2] * S1, r[3] + a[3] * S1};
            NTS(yrow + col, o);
        }
    }

    // ---- phase 3: v1 (3 interleaved channels, 128x128), streamed per channel ----
    short8 vf[3][4];
#pragma unroll
    for (int c = 0; c < 3; c++) {
        short8 xf1c[4];
#pragma unroll
        for (int kt = 0; kt < 4; kt++) {
            float b[24];
            const float* p = xrow + 256 + 3 * (kt * 32 + q * 8);
#pragma unroll
            for (int i = 0; i < 6; i++) *(fv4*)(b + 4 * i) = *(const fv4*)(p + 4 * i);
            xf1c[kt] = mk8(pk2(b[c], b[c+3]), pk2(b[c+6], b[c+9]),
                           pk2(b[c+12], b[c+15]), pk2(b[c+18], b[c+21]));
        }
#pragma unroll
        for (int tp = 0; tp < 4; tp++) {
            f32x4 a0 = {0.f,0.f,0.f,0.f}, a1 = {0.f,0.f,0.f,0.f};
#pragma unroll
            for (int kt = 0; kt < 4; kt++) {
                a0 = MFMA(pw1v1[(kt * 8 + 2 * tp + 0) * 64 + lane], xf1c[kt], a0);
                a1 = MFMA(pw1v1[(kt * 8 + 2 * tp + 1) * 64 + lane], xf1c[kt], a1);
            }
#pragma unroll
            for (int h = 0; h < 2; h++) {
                f32x4 a = h ? a1 : a0;
                int t = 2 * tp + h;
                f32x4 g = gacc[t];
                Sd[dwb + t * 8]     = pk2(a[0]*SV1*g[0], a[1]*SV1*g[1]);
                Sd[dwb + t * 8 + 1] = pk2(a[2]*SV1*g[2], a[3]*SV1*g[3]);
            }
        }
        WSYNC();   // writes done before fragment reads
#pragma unroll
        for (int kt = 0; kt < 4; kt++)
            vf[c][kt] = *(const short8*)(Sr + kt * 32);
        WSYNC();   // reads landed before next channel overwrites the slot
    }
#pragma unroll 1
    for (int t = 0; t < 8; t++) {
        f32x4 ac0 = {0.f,0.f,0.f,0.f}, ac1 = {0.f,0.f,0.f,0.f}, ac2 = {0.f,0.f,0.f,0.f};
#pragma unroll
        for (int kt = 0; kt < 4; kt++) {
            short8 w = pw2v1[(kt * 8 + t) * 64 + lane];
            ac0 = MFMA(w, vf[0][kt], ac0);
            ac1 = MFMA(w, vf[1][kt], ac1);
            ac2 = MFMA(w, vf[2][kt], ac2);
        }
        int base = 256 + 3 * (t * 16 + q * 4);
        fv4 r0 = NTL(xrow + base), r1 = NTL(xrow + base + 4), r2 = NTL(xrow + base + 8);
        fv4 o0 = {r0[0]+ac0[0]*SV1, r0[1]+ac1[0]*SV1, r0[2]+ac2[0]*SV1, r0[3]+ac0[1]*SV1};
        fv4 o1 = {r1[0]+ac1[1]*SV1, r1[1]+ac2[1]*SV1, r1[2]+ac0[2]*SV1, r1[3]+ac1[2]*SV1};
        fv4 o2 = {r2[0]+ac2[2]*SV1, r2[1]+ac0[3]*SV1, r2[2]+ac1[3]*SV1, r2[3]+ac2[3]*SV1};
        NTS(yrow + base, o0); NTS(yrow + base + 4, o1); NTS(yrow + base + 8, o2);
    }

    // ---- phase 4: v2 (5 interleaved channels, 64x64), streamed per channel ----
    short8 vf2[5][2];
#pragma unroll
    for (int c = 0; c < 5; c++) {
        short8 xf2c[2];
#pragma unroll
        for (int kt = 0; kt < 2; kt++) {
            float b[40];
            const float* p = xrow + 640 + 5 * (kt * 32 + q * 8);
#pragma unroll
            for (int i = 0; i < 10; i++) *(fv4*)(b + 4 * i) = *(const fv4*)(p + 4 * i);
            xf2c[kt] = mk8(pk2(b[c], b[c+5]), pk2(b[c+10], b[c+15]),
                           pk2(b[c+20], b[c+25]), pk2(b[c+30], b[c+35]));
        }
#pragma unroll
        for (int tp = 0; tp < 2; tp++) {
            f32x4 a0 = {0.f,0.f,0.f,0.f}, a1 = {0.f,0.f,0.f,0.f};
#pragma unroll
            for (int kt = 0; kt < 2; kt++) {
                a0 = MFMA(pw1v2[(kt * 4 + 2 * tp + 0) * 64 + lane], xf2c[kt], a0);
                a1 = MFMA(pw1v2[(kt * 4 + 2 * tp + 1) * 64 + lane], xf2c[kt], a1);
            }
#pragma unroll
            for (int h = 0; h < 2; h++) {
                f32x4 a = h ? a1 : a0;
                int t = 2 * tp + h;
                f32x4 g = gacc[8 + t];
                Sd[dwb + t * 8]     = pk2(a[0]*SV2*g[0], a[1]*SV2*g[1]);
                Sd[dwb + t * 8 + 1] = pk2(a[2]*SV2*g[2], a[3]*SV2*g[3]);
            }
        }
        WSYNC();
#pragma unroll
        for (int kt = 0; kt < 2; kt++)
            vf2[c][kt] = *(const short8*)(Sr + kt * 32);
        WSYNC();
    }
#pragma unroll 1
    for (int t = 0; t < 4; t++) {
        f32x4 b0 = {0.f,0.f,0.f,0.f}, b1 = {0.f,0.f,0.f,0.f}, b2 = {0.f,0.f,0.f,0.f},
              b3 = {0.f,0.f,0.f,0.f}, b4 = {0.f,0.f,0.f,0.f};
#pragma unroll
        for (int kt = 0; kt < 2; kt++) {
            short8 w = pw2v2[(kt * 4 + t) * 64 + lane];
            b0 = MFMA(w, vf2[0][kt], b0);
            b1 = MFMA(w, vf2[1][kt], b1);
            b2 = MFMA(w, vf2[2][kt], b2);
            b3 = MFMA(w, vf2[3][kt], b3);
            b4 = MFMA(w, vf2[4][kt], b4);
        }
        int base = 640 + 5 * (t * 16 + q * 4);
        fv4 r0 = NTL(xrow + base),      r1 = NTL(xrow + base + 4),
            r2 = NTL(xrow + base + 8),  r3 = NTL(xrow + base + 12),
            r4 = NTL(xrow + base + 16);
        fv4 o0 = {r0[0]+b0[0]*SV2, r0[1]+b1[0]*SV2, r0[2]+b2[0]*SV2, r0[3]+b3[0]*SV2};
        fv4 o1 = {r1[0]+b4[0]*SV2, r1[1]+b0[1]*SV2, r1[2]+b1[1]*SV2, r1[3]+b2[1]*SV2};
        fv4 o2 = {r2[0]+b3[1]*SV2, r2[1]+b4[1]*SV2, r2[2]+b0[2]*SV2, r2[3]+b1[2]*SV2};
        fv4 o3 = {r3[0]+b2[2]*SV2, r3[1]+b3[2]*SV2, r3[2]+b4[2]*SV2, r3[3]+b0[3]*SV2};
        fv4 o4 = {r4[0]+b1[3]*SV2, r4[1]+b2[3]*SV2, r4[2]+b3[3]*SV2, r4[3]+b4[3]*SV2};
        NTS(yrow + base, o0); NTS(yrow + base + 4, o1); NTS(yrow + base + 8, o2);
        NTS(yrow + base + 12, o3); NTS(yrow + base + 16, o4);
    }
}

static float compute_cssp() {
    const int N = 200001;
    const double dz = 20.0 / 200000.0;
    double sum = 0.0;
    for (int i = 0; i < N; i++) {
        double z = -10.0 + dz * i;
        double f = (z > 0 ? z : 0.0) + log1p(exp(-fabs(z))) - 0.69314718055994530942;
        double phi = exp(-0.5 * z * z) * 0.39894228040143267794;
        double y = f * f * phi;
        sum += (i == 0 || i == N - 1) ? 0.5 * y : y;
    }
    return (float)(1.0 / sqrt(sum * dz));
}

extern "C" void kernel_launch(void* const* d_in, const int* in_sizes, int n_in,
                              void* d_out, int out_size, void* d_ws, size_t ws_size,
                              hipStream_t stream) {
    const float* x    = (const float*)d_in[0];
    const float* w1s  = (const float*)d_in[1];
    const float* w1v1 = (const float*)d_in[2];
    const float* w1v2 = (const float*)d_in[3];
    const float* w2s  = (const float*)d_in[4];
    const float* w2v1 = (const float*)d_in[5];
    const float* w2v2 = (const float*)d_in[6];
    float* out = (float*)d_out;

    static const float c_ssp = compute_cssp();

    int rows = in_sizes[0] / XP;
    int blocks = rows / 64;

    pack_weights<<<108, 256, 0, stream>>>(w1s, w1v1, w1v2, w2s, w2v1, w2v2);
    fused_kernel<<<blocks, 256, 0, stream>>>(x, out, c_ssp);
}

// Round 2
// 631.758 us; speedup vs baseline: 1.0794x; 1.0794x over previous
//
#include <hip/hip_runtime.h>
#include <math.h>

#define XP 960
typedef __attribute__((ext_vector_type(8))) short short8;
typedef __attribute__((ext_vector_type(4))) float f32x4;
typedef __attribute__((ext_vector_type(4))) float fv4;
typedef __attribute__((ext_vector_type(4))) unsigned uint4v;

// Packed bf16 weights in MFMA fragment order (serves as B-frag for X@W and
// identically as A-frag for W^T@X^T). Offsets in shorts:
//  w1s:0  w1v1:114688  w1v2:131072  w2s:135168  w2v1:200704  w2v2:217088
__device__ short g_pack[221184];

__device__ __forceinline__ short f2bf(float f) {
    union { float f; unsigned u; } v; v.f = f;
    unsigned r = (v.u + 0x7fffu + ((v.u >> 16) & 1u)) >> 16;
    return (short)r;
}
// pack two floats -> dword of 2 bf16 (round-to-nearest, half-up)
__device__ __forceinline__ unsigned pk2(float a, float b) {
    union { float f; unsigned u; } x, y; x.f = a; y.f = b;
    return ((x.u + 0x8000u) >> 16) | ((y.u + 0x8000u) & 0xffff0000u);
}
__device__ __forceinline__ short8 mk8(unsigned d0, unsigned d1, unsigned d2, unsigned d3) {
    union { uint4v u; short8 s; } cv;
    cv.u = (uint4v){d0, d1, d2, d3};
    return cv.s;
}
__device__ __forceinline__ float ssp(float v, float c) {
    // c * (softplus(v) - ln2), stable: max(v,0) + ln2*log2(1 + 2^(-|v|*log2e))
    float t = exp2f(fabsf(v) * -1.44269504088896340736f);
    float sp = fmaxf(v, 0.f) + 0.69314718055994530942f * __log2f(1.0f + t);
    return c * (sp - 0.69314718055994530942f);
}

#define WSYNC() asm volatile("s_waitcnt lgkmcnt(0)" ::: "memory")
#define MFMA(a, b, c) __builtin_amdgcn_mfma_f32_16x16x32_bf16((a), (b), (c), 0, 0, 0)
#define NTL(p) __builtin_nontemporal_load((const fv4*)(p))
// Plain stores (NOT nontemporal): let L2 write-combine the 48B/320B-per-row
// epilogue patterns into full lines. (Round-1 NT stores: WRITE_SIZE 450 MB
// vs 252 MB output — testing NT as the amplification cause.)
#define STS(p, v) (*(fv4*)(p) = (v))

__global__ void pack_weights(const float* __restrict__ w1s, const float* __restrict__ w1v1,
                             const float* __restrict__ w1v2, const float* __restrict__ w2s,
                             const float* __restrict__ w2v1, const float* __restrict__ w2v2) {
    int g = blockIdx.x * blockDim.x + threadIdx.x;
    const float* src; int NT, N, dstoff, lg;
    if      (g < 14336) { src = w1s;  NT = 28; N = 448; dstoff = 0;      lg = g; }
    else if (g < 16384) { src = w1v1; NT = 8;  N = 128; dstoff = 114688; lg = g - 14336; }
    else if (g < 16896) { src = w1v2; NT = 4;  N = 64;  dstoff = 131072; lg = g - 16384; }
    else if (g < 25088) { src = w2s;  NT = 16; N = 256; dstoff = 135168; lg = g - 16896; }
    else if (g < 27136) { src = w2v1; NT = 8;  N = 128; dstoff = 200704; lg = g - 25088; }
    else if (g < 27648) { src = w2v2; NT = 4;  N = 64;  dstoff = 217088; lg = g - 27136; }
    else return;
    int lane = lg & 63;
    int t = lg >> 6;
    int nt = t % NT;
    int kt = t / NT;
    int k0 = kt * 32 + (lane >> 4) * 8;
    int n  = nt * 16 + (lane & 15);
    short* dst = g_pack + dstoff + (size_t)lg * 8;
#pragma unroll
    for (int j = 0; j < 8; j++) dst[j] = f2bf(src[(size_t)(k0 + j) * N + n]);
}

// LDS 33792/block -> 4 blocks/CU; 1024-block grid fully resident, no tail.
__global__ __launch_bounds__(256, 4) void fused_kernel(const float* __restrict__ x,
                                                       float* __restrict__ out,
                                                       float c_ssp) {
    // One per-wave arena; per-sample pitch 264 shorts (528 B, 16B-aligned,
    // 528 % 128 = 16 so consecutive samples rotate banks -> only 2-way alias).
    // The SAME slot [0..k) per sample is reused sequentially:
    //   scalars (256 sh) -> v1 channels (128 sh each, one at a time)
    //   -> v2 channels (64 sh each, one at a time).
    // x is loaded from global exactly ONCE per phase; all channels' fragments
    // are packed to registers up front (round-1's per-channel x re-read cost
    // +134 MB FETCH = +64 us).
    // Safety: per-wave DS ops execute in order; WSYNC ("memory" clobber +
    // lgkmcnt(0)) fences the compiler between write-group / read-group / reuse.
    __shared__ __align__(16) short arena[4][16 * 264];

    const int lane = threadIdx.x & 63;
    const int wave = threadIdx.x >> 6;
    const int q = lane >> 4, l15 = lane & 15;
    const int row0 = blockIdx.x * 64 + wave * 16;
    short* S = arena[wave];
    unsigned* Sd = (unsigned*)S;
    const int dwb = l15 * 132 + q * 2;        // dword base for C-layout pair-stores
    const short* Sr = S + l15 * 264 + q * 8;  // b128 read base (k = kt*32+q*8)

    const short8* pw1s  = (const short8*)(g_pack + 0);
    const short8* pw1v1 = (const short8*)(g_pack + 114688);
    const short8* pw1v2 = (const short8*)(g_pack + 131072);
    const short8* pw2s  = (const short8*)(g_pack + 135168);
    const short8* pw2v1 = (const short8*)(g_pack + 200704);
    const short8* pw2v2 = (const short8*)(g_pack + 217088);

    const float* xrow = x + (size_t)(row0 + l15) * XP;
    float* yrow = out + (size_t)(row0 + l15) * XP;

    const float S1  = 0.0625f;                // 1/sqrt(256)
    const float SV1 = 0.08838834764831845f;   // 1/sqrt(128)
    const float SV2 = 0.125f;                 // 1/sqrt(64)

    // ---- phase 0: x0 fragments (lane = own sample row; serves as B operand) ----
    short8 xf0[8];
#pragma unroll
    for (int kt = 0; kt < 8; kt++) {
        fv4 u0 = *(const fv4*)(xrow + kt * 32 + q * 8);
        fv4 u1 = *(const fv4*)(xrow + kt * 32 + q * 8 + 4);
        xf0[kt] = mk8(pk2(u0[0], u0[1]), pk2(u0[2], u0[3]), pk2(u1[0], u1[1]), pk2(u1[2], u1[3]));
    }

    // ---- phase 1: S^T = W1s^T X0^T ; scalars -> LDS (B-layout), gates -> regs ----
#pragma unroll 1
    for (int tp = 0; tp < 8; tp++) {          // scalar tiles t = 0..15
        f32x4 a0 = {0.f,0.f,0.f,0.f}, a1 = {0.f,0.f,0.f,0.f};
#pragma unroll
        for (int kt = 0; kt < 8; kt++) {
            a0 = MFMA(pw1s[(kt * 28 + 2 * tp + 0) * 64 + lane], xf0[kt], a0);
            a1 = MFMA(pw1s[(kt * 28 + 2 * tp + 1) * 64 + lane], xf0[kt], a1);
        }
#pragma unroll
        for (int h = 0; h < 2; h++) {
            f32x4 a = h ? a1 : a0;
            int t = 2 * tp + h;
            Sd[dwb + t * 8]     = pk2(ssp(a[0] * S1, c_ssp), ssp(a[1] * S1, c_ssp));
            Sd[dwb + t * 8 + 1] = pk2(ssp(a[2] * S1, c_ssp), ssp(a[3] * S1, c_ssp));
        }
    }
    f32x4 gacc[12];
#pragma unroll
    for (int tp = 0; tp < 6; tp++) {          // gate tiles t = 16..27 (static gacc idx)
        f32x4 a0 = {0.f,0.f,0.f,0.f}, a1 = {0.f,0.f,0.f,0.f};
#pragma unroll
        for (int kt = 0; kt < 8; kt++) {
            a0 = MFMA(pw1s[(kt * 28 + 16 + 2 * tp + 0) * 64 + lane], xf0[kt], a0);
            a1 = MFMA(pw1s[(kt * 28 + 16 + 2 * tp + 1) * 64 + lane], xf0[kt], a1);
        }
        gacc[2 * tp]     = (f32x4){ssp(a0[0]*S1,c_ssp), ssp(a0[1]*S1,c_ssp), ssp(a0[2]*S1,c_ssp), ssp(a0[3]*S1,c_ssp)};
        gacc[2 * tp + 1] = (f32x4){ssp(a1[0]*S1,c_ssp), ssp(a1[1]*S1,c_ssp), ssp(a1[2]*S1,c_ssp), ssp(a1[3]*S1,c_ssp)};
    }
    WSYNC();

    // ---- phase 2: Y0^T = W2s^T Scal^T ; epilogue = per-lane float4 on own row ----
    short8 sf[8];
#pragma unroll
    for (int kt = 0; kt < 8; kt++) sf[kt] = *(const short8*)(Sr + kt * 32);
    WSYNC();   // fence: scalar reads complete before v1 reuses the slot
#pragma unroll 1
    for (int tp = 0; tp < 8; tp++) {
        f32x4 a0 = {0.f,0.f,0.f,0.f}, a1 = {0.f,0.f,0.f,0.f};
#pragma unroll
        for (int kt = 0; kt < 8; kt++) {
            a0 = MFMA(pw2s[(kt * 16 + 2 * tp + 0) * 64 + lane], sf[kt], a0);
            a1 = MFMA(pw2s[(kt * 16 + 2 * tp + 1) * 64 + lane], sf[kt], a1);
        }
#pragma unroll
        for (int h = 0; h < 2; h++) {
            f32x4 a = h ? a1 : a0;
            int col = (2 * tp + h) * 16 + q * 4;
            fv4 r = NTL(xrow + col);
            fv4 o = {r[0] + a[0] * S1, r[1] + a[1] * S1, r[2] + a[2] * S1, r[3] + a[3] * S1};
            STS(yrow + col, o);
        }
    }

    // ---- phase 3: v1 (3 channels) — x loaded ONCE, channels streamed via LDS ----
    short8 xf1[3][4];
#pragma unroll
    for (int kt = 0; kt < 4; kt++) {
        float b[24];
        const float* p = xrow + 256 + 3 * (kt * 32 + q * 8);
#pragma unroll
        for (int i = 0; i < 6; i++) *(fv4*)(b + 4 * i) = *(const fv4*)(p + 4 * i);
#pragma unroll
        for (int c = 0; c < 3; c++)
            xf1[c][kt] = mk8(pk2(b[c], b[c+3]), pk2(b[c+6], b[c+9]),
                             pk2(b[c+12], b[c+15]), pk2(b[c+18], b[c+21]));
    }
    short8 vf[3][4];
#pragma unroll
    for (int c = 0; c < 3; c++) {
#pragma unroll
        for (int tp = 0; tp < 4; tp++) {
            f32x4 a0 = {0.f,0.f,0.f,0.f}, a1 = {0.f,0.f,0.f,0.f};
#pragma unroll
            for (int kt = 0; kt < 4; kt++) {
                a0 = MFMA(pw1v1[(kt * 8 + 2 * tp + 0) * 64 + lane], xf1[c][kt], a0);
                a1 = MFMA(pw1v1[(kt * 8 + 2 * tp + 1) * 64 + lane], xf1[c][kt], a1);
            }
#pragma unroll
            for (int h = 0; h < 2; h++) {
                f32x4 a = h ? a1 : a0;
                int t = 2 * tp + h;
                f32x4 g = gacc[t];
                Sd[dwb + t * 8]     = pk2(a[0]*SV1*g[0], a[1]*SV1*g[1]);
                Sd[dwb + t * 8 + 1] = pk2(a[2]*SV1*g[2], a[3]*SV1*g[3]);
            }
        }
        WSYNC();   // writes done before fragment reads
#pragma unroll
        for (int kt = 0; kt < 4; kt++)
            vf[c][kt] = *(const short8*)(Sr + kt * 32);
        WSYNC();   // reads landed before next channel overwrites the slot
    }
#pragma unroll 1
    for (int t = 0; t < 8; t++) {
        f32x4 ac0 = {0.f,0.f,0.f,0.f}, ac1 = {0.f,0.f,0.f,0.f}, ac2 = {0.f,0.f,0.f,0.f};
#pragma unroll
        for (int kt = 0; kt < 4; kt++) {
            short8 w = pw2v1[(kt * 8 + t) * 64 + lane];
            ac0 = MFMA(w, vf[0][kt], ac0);
            ac1 = MFMA(w, vf[1][kt], ac1);
            ac2 = MFMA(w, vf[2][kt], ac2);
        }
        int base = 256 + 3 * (t * 16 + q * 4);
        fv4 r0 = NTL(xrow + base), r1 = NTL(xrow + base + 4), r2 = NTL(xrow + base + 8);
        fv4 o0 = {r0[0]+ac0[0]*SV1, r0[1]+ac1[0]*SV1, r0[2]+ac2[0]*SV1, r0[3]+ac0[1]*SV1};
        fv4 o1 = {r1[0]+ac1[1]*SV1, r1[1]+ac2[1]*SV1, r1[2]+ac0[2]*SV1, r1[3]+ac1[2]*SV1};
        fv4 o2 = {r2[0]+ac2[2]*SV1, r2[1]+ac0[3]*SV1, r2[2]+ac1[3]*SV1, r2[3]+ac2[3]*SV1};
        STS(yrow + base, o0); STS(yrow + base + 4, o1); STS(yrow + base + 8, o2);
    }

    // ---- phase 4: v2 (5 channels) — x loaded ONCE, channels streamed via LDS ----
    short8 xf2[5][2];
#pragma unroll
    for (int kt = 0; kt < 2; kt++) {
        float b[40];
        const float* p = xrow + 640 + 5 * (kt * 32 + q * 8);
#pragma unroll
        for (int i = 0; i < 10; i++) *(fv4*)(b + 4 * i) = *(const fv4*)(p + 4 * i);
#pragma unroll
        for (int c = 0; c < 5; c++)
            xf2[c][kt] = mk8(pk2(b[c], b[c+5]), pk2(b[c+10], b[c+15]),
                             pk2(b[c+20], b[c+25]), pk2(b[c+30], b[c+35]));
    }
    short8 vf2[5][2];
#pragma unroll
    for (int c = 0; c < 5; c++) {
#pragma unroll
        for (int tp = 0; tp < 2; tp++) {
            f32x4 a0 = {0.f,0.f,0.f,0.f}, a1 = {0.f,0.f,0.f,0.f};
#pragma unroll
            for (int kt = 0; kt < 2; kt++) {
                a0 = MFMA(pw1v2[(kt * 4 + 2 * tp + 0) * 64 + lane], xf2[c][kt], a0);
                a1 = MFMA(pw1v2[(kt * 4 + 2 * tp + 1) * 64 + lane], xf2[c][kt], a1);
            }
#pragma unroll
            for (int h = 0; h < 2; h++) {
                f32x4 a = h ? a1 : a0;
                int t = 2 * tp + h;
                f32x4 g = gacc[8 + t];
                Sd[dwb + t * 8]     = pk2(a[0]*SV2*g[0], a[1]*SV2*g[1]);
                Sd[dwb + t * 8 + 1] = pk2(a[2]*SV2*g[2], a[3]*SV2*g[3]);
            }
        }
        WSYNC();
#pragma unroll
        for (int kt = 0; kt < 2; kt++)
            vf2[c][kt] = *(const short8*)(Sr + kt * 32);
        WSYNC();
    }
#pragma unroll 1
    for (int t = 0; t < 4; t++) {
        f32x4 b0 = {0.f,0.f,0.f,0.f}, b1 = {0.f,0.f,0.f,0.f}, b2 = {0.f,0.f,0.f,0.f},
              b3 = {0.f,0.f,0.f,0.f}, b4 = {0.f,0.f,0.f,0.f};
#pragma unroll
        for (int kt = 0; kt < 2; kt++) {
            short8 w = pw2v2[(kt * 4 + t) * 64 + lane];
            b0 = MFMA(w, vf2[0][kt], b0);
            b1 = MFMA(w, vf2[1][kt], b1);
            b2 = MFMA(w, vf2[2][kt], b2);
            b3 = MFMA(w, vf2[3][kt], b3);
            b4 = MFMA(w, vf2[4][kt], b4);
        }
        int base = 640 + 5 * (t * 16 + q * 4);
        fv4 r0 = NTL(xrow + base),      r1 = NTL(xrow + base + 4),
            r2 = NTL(xrow + base + 8),  r3 = NTL(xrow + base + 12),
            r4 = NTL(xrow + base + 16);
        fv4 o0 = {r0[0]+b0[0]*SV2, r0[1]+b1[0]*SV2, r0[2]+b2[0]*SV2, r0[3]+b3[0]*SV2};
        fv4 o1 = {r1[0]+b4[0]*SV2, r1[1]+b0[1]*SV2, r1[2]+b1[1]*SV2, r1[3]+b2[1]*SV2};
        fv4 o2 = {r2[0]+b3[1]*SV2, r2[1]+b4[1]*SV2, r2[2]+b0[2]*SV2, r2[3]+b1[2]*SV2};
        fv4 o3 = {r3[0]+b2[2]*SV2, r3[1]+b3[2]*SV2, r3[2]+b4[2]*SV2, r3[3]+b0[3]*SV2};
        fv4 o4 = {r4[0]+b1[3]*SV2, r4[1]+b2[3]*SV2, r4[2]+b3[3]*SV2, r4[3]+b4[3]*SV2};
        STS(yrow + base, o0); STS(yrow + base + 4, o1); STS(yrow + base + 8, o2);
        STS(yrow + base + 12, o3); STS(yrow + base + 16, o4);
    }
}

static float compute_cssp() {
    const int N = 200001;
    const double dz = 20.0 / 200000.0;
    double sum = 0.0;
    for (int i = 0; i < N; i++) {
        double z = -10.0 + dz * i;
        double f = (z > 0 ? z : 0.0) + log1p(exp(-fabs(z))) - 0.69314718055994530942;
        double phi = exp(-0.5 * z * z) * 0.39894228040143267794;
        double y = f * f * phi;
        sum += (i == 0 || i == N - 1) ? 0.5 * y : y;
    }
    return (float)(1.0 / sqrt(sum * dz));
}

extern "C" void kernel_launch(void* const* d_in, const int* in_sizes, int n_in,
                              void* d_out, int out_size, void* d_ws, size_t ws_size,
                              hipStream_t stream) {
    const float* x    = (const float*)d_in[0];
    const float* w1s  = (const float*)d_in[1];
    const float* w1v1 = (const float*)d_in[2];
    const float* w1v2 = (const float*)d_in[3];
    const float* w2s  = (const float*)d_in[4];
    const float* w2v1 = (const float*)d_in[5];
    const float* w2v2 = (const float*)d_in[6];
    float* out = (float*)d_out;

    static const float c_ssp = compute_cssp();

    int rows = in_sizes[0] / XP;
    int blocks = rows / 64;

    pack_weights<<<108, 256, 0, stream>>>(w1s, w1v1, w1v2, w2s, w2v1, w2v2);
    fused_kernel<<<blocks, 256, 0, stream>>>(x, out, c_ssp);
}

// Round 3
// 615.492 us; speedup vs baseline: 1.1079x; 1.0264x over previous
//
#include <hip/hip_runtime.h>
#include <math.h>

#define XP 960
typedef __attribute__((ext_vector_type(8))) short short8;
typedef __attribute__((ext_vector_type(4))) float f32x4;
typedef __attribute__((ext_vector_type(4))) float fv4;
typedef __attribute__((ext_vector_type(4))) unsigned uint4v;

// Packed bf16 weights in MFMA fragment order (serves as B-frag for X@W and
// identically as A-frag for W^T@X^T). Offsets in shorts:
//  w1s:0  w1v1:114688  w1v2:131072  w2s:135168  w2v1:200704  w2v2:217088
__device__ short g_pack[221184];

__device__ __forceinline__ short f2bf(float f) {
    union { float f; unsigned u; } v; v.f = f;
    unsigned r = (v.u + 0x7fffu + ((v.u >> 16) & 1u)) >> 16;
    return (short)r;
}
// pack two floats -> dword of 2 bf16 (round-to-nearest, half-up)
__device__ __forceinline__ unsigned pk2(float a, float b) {
    union { float f; unsigned u; } x, y; x.f = a; y.f = b;
    return ((x.u + 0x8000u) >> 16) | ((y.u + 0x8000u) & 0xffff0000u);
}
__device__ __forceinline__ short8 mk8(unsigned d0, unsigned d1, unsigned d2, unsigned d3) {
    union { uint4v u; short8 s; } cv;
    cv.u = (uint4v){d0, d1, d2, d3};
    return cv.s;
}
// unpack lo/hi bf16 of a packed dword to float
__device__ __forceinline__ float bflo(unsigned d) {
    union { unsigned u; float f; } v; v.u = d << 16; return v.f;
}
__device__ __forceinline__ float bfhi(unsigned d) {
    union { unsigned u; float f; } v; v.u = d & 0xffff0000u; return v.f;
}
__device__ __forceinline__ float ssp(float v, float c) {
    // c * (softplus(v) - ln2), stable: max(v,0) + ln2*log2(1 + 2^(-|v|*log2e))
    float t = exp2f(fabsf(v) * -1.44269504088896340736f);
    float sp = fmaxf(v, 0.f) + 0.69314718055994530942f * __log2f(1.0f + t);
    return c * (sp - 0.69314718055994530942f);
}

#define WSYNC() asm volatile("s_waitcnt lgkmcnt(0)" ::: "memory")
#define MFMA(a, b, c) __builtin_amdgcn_mfma_f32_16x16x32_bf16((a), (b), (c), 0, 0, 0)
#define NTL(p) __builtin_nontemporal_load((const fv4*)(p))
#define STS(p, v) (*(fv4*)(p) = (v))

__global__ void pack_weights(const float* __restrict__ w1s, const float* __restrict__ w1v1,
                             const float* __restrict__ w1v2, const float* __restrict__ w2s,
                             const float* __restrict__ w2v1, const float* __restrict__ w2v2) {
    int g = blockIdx.x * blockDim.x + threadIdx.x;
    const float* src; int NT, N, dstoff, lg;
    if      (g < 14336) { src = w1s;  NT = 28; N = 448; dstoff = 0;      lg = g; }
    else if (g < 16384) { src = w1v1; NT = 8;  N = 128; dstoff = 114688; lg = g - 14336; }
    else if (g < 16896) { src = w1v2; NT = 4;  N = 64;  dstoff = 131072; lg = g - 16384; }
    else if (g < 25088) { src = w2s;  NT = 16; N = 256; dstoff = 135168; lg = g - 16896; }
    else if (g < 27136) { src = w2v1; NT = 8;  N = 128; dstoff = 200704; lg = g - 25088; }
    else if (g < 27648) { src = w2v2; NT = 4;  N = 64;  dstoff = 217088; lg = g - 27136; }
    else return;
    int lane = lg & 63;
    int t = lg >> 6;
    int nt = t % NT;
    int kt = t / NT;
    int k0 = kt * 32 + (lane >> 4) * 8;
    int n  = nt * 16 + (lane & 15);
    short* dst = g_pack + dstoff + (size_t)lg * 8;
#pragma unroll
    for (int j = 0; j < 8; j++) dst[j] = f2bf(src[(size_t)(k0 + j) * N + n]);
}

// 32 samples/wave (two 16-sample halves A/B sharing every weight fragment):
// halves weight-load traffic per sample, doubles independent MFMA chains.
// LDS = exactly 64 KiB -> 2 blocks/CU x 4 waves = 8 waves/CU; grid 512 = fully
// resident. Per-sample LDS pitch 256 shorts with XOR swizzle
// byte ^= (sample&7)<<4 (identical on write+read; b128 reads conflict-free).
__global__ __launch_bounds__(256, 2) void fused_kernel(const float* __restrict__ x,
                                                       float* __restrict__ out,
                                                       float c_ssp) {
    __shared__ __align__(16) short arena[4][32 * 256];   // 65536 B

    const int lane = threadIdx.x & 63;
    const int wave = threadIdx.x >> 6;
    const int q = lane >> 4, l15 = lane & 15;
    const int row0 = blockIdx.x * 128 + wave * 32;
    short* S = arena[wave];
    unsigned* Sd = (unsigned*)S;

    // swizzle: (s&7) identical for s=l15 and s=l15+16
    const unsigned swzd = (unsigned)((l15 & 7) << 2);   // dword-space mask (bits 2-4)
    const int wlinA = l15 * 128 + q * 2;                // dword linear store base, half A
    const int wlinB = wlinA + 2048;                     // +16*128
    const int rlinA = l15 * 512 + q * 16;               // byte linear read base, half A
    const int rlinB = rlinA + 8192;
#define LDSR(linbyte) (*(const short8*)((const char*)S + (((unsigned)(linbyte)) ^ (swzd << 2))))

    const short8* pw1s  = (const short8*)(g_pack + 0);
    const short8* pw1v1 = (const short8*)(g_pack + 114688);
    const short8* pw1v2 = (const short8*)(g_pack + 131072);
    const short8* pw2s  = (const short8*)(g_pack + 135168);
    const short8* pw2v1 = (const short8*)(g_pack + 200704);
    const short8* pw2v2 = (const short8*)(g_pack + 217088);

    const float* xrowA = x + (size_t)(row0 + l15) * XP;
    const float* xrowB = xrowA + (size_t)16 * XP;
    float* yrowA = out + (size_t)(row0 + l15) * XP;
    float* yrowB = yrowA + (size_t)16 * XP;

    const float S1  = 0.0625f;                // 1/sqrt(256)
    const float SV1 = 0.08838834764831845f;   // 1/sqrt(128)
    const float SV2 = 0.125f;                 // 1/sqrt(64)

    // ---- phase 0: x0 fragments for both halves ----
    short8 xfA[8], xfB[8];
#pragma unroll
    for (int kt = 0; kt < 8; kt++) {
        fv4 a0 = *(const fv4*)(xrowA + kt * 32 + q * 8);
        fv4 a1 = *(const fv4*)(xrowA + kt * 32 + q * 8 + 4);
        fv4 b0 = *(const fv4*)(xrowB + kt * 32 + q * 8);
        fv4 b1 = *(const fv4*)(xrowB + kt * 32 + q * 8 + 4);
        xfA[kt] = mk8(pk2(a0[0], a0[1]), pk2(a0[2], a0[3]), pk2(a1[0], a1[1]), pk2(a1[2], a1[3]));
        xfB[kt] = mk8(pk2(b0[0], b0[1]), pk2(b0[2], b0[3]), pk2(b1[0], b1[1]), pk2(b1[2], b1[3]));
    }

    // ---- phase 1: scalars -> LDS (both halves); each weight frag feeds 2 MFMA ----
#pragma unroll 1
    for (int tp = 0; tp < 8; tp++) {          // scalar tiles t = 0..15
        f32x4 a0A = {0.f,0.f,0.f,0.f}, a1A = {0.f,0.f,0.f,0.f};
        f32x4 a0B = {0.f,0.f,0.f,0.f}, a1B = {0.f,0.f,0.f,0.f};
#pragma unroll
        for (int kt = 0; kt < 8; kt++) {
            short8 w0 = pw1s[(kt * 28 + 2 * tp + 0) * 64 + lane];
            short8 w1 = pw1s[(kt * 28 + 2 * tp + 1) * 64 + lane];
            a0A = MFMA(w0, xfA[kt], a0A);
            a0B = MFMA(w0, xfB[kt], a0B);
            a1A = MFMA(w1, xfA[kt], a1A);
            a1B = MFMA(w1, xfB[kt], a1B);
        }
#pragma unroll
        for (int h = 0; h < 2; h++) {
            f32x4 aA = h ? a1A : a0A, aB = h ? a1B : a0B;
            int t = 2 * tp + h;
            { unsigned i = ((unsigned)(wlinA + t * 8)) ^ swzd;
              Sd[i]     = pk2(ssp(aA[0] * S1, c_ssp), ssp(aA[1] * S1, c_ssp));
              Sd[i + 1] = pk2(ssp(aA[2] * S1, c_ssp), ssp(aA[3] * S1, c_ssp)); }
            { unsigned i = ((unsigned)(wlinB + t * 8)) ^ swzd;
              Sd[i]     = pk2(ssp(aB[0] * S1, c_ssp), ssp(aB[1] * S1, c_ssp));
              Sd[i + 1] = pk2(ssp(aB[2] * S1, c_ssp), ssp(aB[3] * S1, c_ssp)); }
        }
    }
    // gates, packed as bf16 pairs in regs (48 regs for both halves vs 96 f32)
    unsigned gpkA[24], gpkB[24];
#pragma unroll
    for (int tp = 0; tp < 6; tp++) {          // gate tiles t = 16..27
        f32x4 a0A = {0.f,0.f,0.f,0.f}, a1A = {0.f,0.f,0.f,0.f};
        f32x4 a0B = {0.f,0.f,0.f,0.f}, a1B = {0.f,0.f,0.f,0.f};
#pragma unroll
        for (int kt = 0; kt < 8; kt++) {
            short8 w0 = pw1s[(kt * 28 + 16 + 2 * tp + 0) * 64 + lane];
            short8 w1 = pw1s[(kt * 28 + 16 + 2 * tp + 1) * 64 + lane];
            a0A = MFMA(w0, xfA[kt], a0A);
            a0B = MFMA(w0, xfB[kt], a0B);
            a1A = MFMA(w1, xfA[kt], a1A);
            a1B = MFMA(w1, xfB[kt], a1B);
        }
        gpkA[4*tp+0] = pk2(ssp(a0A[0]*S1,c_ssp), ssp(a0A[1]*S1,c_ssp));
        gpkA[4*tp+1] = pk2(ssp(a0A[2]*S1,c_ssp), ssp(a0A[3]*S1,c_ssp));
        gpkA[4*tp+2] = pk2(ssp(a1A[0]*S1,c_ssp), ssp(a1A[1]*S1,c_ssp));
        gpkA[4*tp+3] = pk2(ssp(a1A[2]*S1,c_ssp), ssp(a1A[3]*S1,c_ssp));
        gpkB[4*tp+0] = pk2(ssp(a0B[0]*S1,c_ssp), ssp(a0B[1]*S1,c_ssp));
        gpkB[4*tp+1] = pk2(ssp(a0B[2]*S1,c_ssp), ssp(a0B[3]*S1,c_ssp));
        gpkB[4*tp+2] = pk2(ssp(a1B[0]*S1,c_ssp), ssp(a1B[1]*S1,c_ssp));
        gpkB[4*tp+3] = pk2(ssp(a1B[2]*S1,c_ssp), ssp(a1B[3]*S1,c_ssp));
    }
    WSYNC();

    // ---- phase 2: Y0^T = W2s^T Scal^T ; epilogue per half ----
    short8 sfA[8], sfB[8];
#pragma unroll
    for (int kt = 0; kt < 8; kt++) {
        sfA[kt] = LDSR(rlinA + kt * 64);
        sfB[kt] = LDSR(rlinB + kt * 64);
    }
    WSYNC();   // reads landed before v1 reuses the slot
#pragma unroll 1
    for (int tp = 0; tp < 8; tp++) {
        f32x4 a0A = {0.f,0.f,0.f,0.f}, a1A = {0.f,0.f,0.f,0.f};
        f32x4 a0B = {0.f,0.f,0.f,0.f}, a1B = {0.f,0.f,0.f,0.f};
#pragma unroll
        for (int kt = 0; kt < 8; kt++) {
            short8 w0 = pw2s[(kt * 16 + 2 * tp + 0) * 64 + lane];
            short8 w1 = pw2s[(kt * 16 + 2 * tp + 1) * 64 + lane];
            a0A = MFMA(w0, sfA[kt], a0A);
            a0B = MFMA(w0, sfB[kt], a0B);
            a1A = MFMA(w1, sfA[kt], a1A);
            a1B = MFMA(w1, sfB[kt], a1B);
        }
#pragma unroll
        for (int h = 0; h < 2; h++) {
            f32x4 aA = h ? a1A : a0A, aB = h ? a1B : a0B;
            int col = (2 * tp + h) * 16 + q * 4;
            fv4 rA = NTL(xrowA + col);
            fv4 oA = {rA[0] + aA[0]*S1, rA[1] + aA[1]*S1, rA[2] + aA[2]*S1, rA[3] + aA[3]*S1};
            STS(yrowA + col, oA);
            fv4 rB = NTL(xrowB + col);
            fv4 oB = {rB[0] + aB[0]*S1, rB[1] + aB[1]*S1, rB[2] + aB[2]*S1, rB[3] + aB[3]*S1};
            STS(yrowB + col, oB);
        }
    }

    // ---- phase 3: v1 (3 channels) — x loaded once, channels streamed via LDS slot ----
    short8 xf1A[3][4], xf1B[3][4];
#pragma unroll
    for (int kt = 0; kt < 4; kt++) {
        float bA[24], bB[24];
        const float* pA = xrowA + 256 + 3 * (kt * 32 + q * 8);
        const float* pB = xrowB + 256 + 3 * (kt * 32 + q * 8);
#pragma unroll
        for (int i = 0; i < 6; i++) {
            *(fv4*)(bA + 4 * i) = *(const fv4*)(pA + 4 * i);
            *(fv4*)(bB + 4 * i) = *(const fv4*)(pB + 4 * i);
        }
#pragma unroll
        for (int c = 0; c < 3; c++) {
            xf1A[c][kt] = mk8(pk2(bA[c], bA[c+3]), pk2(bA[c+6], bA[c+9]),
                              pk2(bA[c+12], bA[c+15]), pk2(bA[c+18], bA[c+21]));
            xf1B[c][kt] = mk8(pk2(bB[c], bB[c+3]), pk2(bB[c+6], bB[c+9]),
                              pk2(bB[c+12], bB[c+15]), pk2(bB[c+18], bB[c+21]));
        }
    }
    short8 vfA[3][4], vfB[3][4];
#pragma unroll
    for (int c = 0; c < 3; c++) {
#pragma unroll
        for (int tp = 0; tp < 4; tp++) {
            f32x4 a0A = {0.f,0.f,0.f,0.f}, a1A = {0.f,0.f,0.f,0.f};
            f32x4 a0B = {0.f,0.f,0.f,0.f}, a1B = {0.f,0.f,0.f,0.f};
#pragma unroll
            for (int kt = 0; kt < 4; kt++) {
                short8 w0 = pw1v1[(kt * 8 + 2 * tp + 0) * 64 + lane];
                short8 w1 = pw1v1[(kt * 8 + 2 * tp + 1) * 64 + lane];
                a0A = MFMA(w0, xf1A[c][kt], a0A);
                a0B = MFMA(w0, xf1B[c][kt], a0B);
                a1A = MFMA(w1, xf1A[c][kt], a1A);
                a1B = MFMA(w1, xf1B[c][kt], a1B);
            }
#pragma unroll
            for (int h = 0; h < 2; h++) {
                f32x4 aA = h ? a1A : a0A, aB = h ? a1B : a0B;
                int t = 2 * tp + h;
                { unsigned i = ((unsigned)(wlinA + t * 8)) ^ swzd;
                  Sd[i]     = pk2(aA[0]*SV1*bflo(gpkA[2*t]),   aA[1]*SV1*bfhi(gpkA[2*t]));
                  Sd[i + 1] = pk2(aA[2]*SV1*bflo(gpkA[2*t+1]), aA[3]*SV1*bfhi(gpkA[2*t+1])); }
                { unsigned i = ((unsigned)(wlinB + t * 8)) ^ swzd;
                  Sd[i]     = pk2(aB[0]*SV1*bflo(gpkB[2*t]),   aB[1]*SV1*bfhi(gpkB[2*t]));
                  Sd[i + 1] = pk2(aB[2]*SV1*bflo(gpkB[2*t+1]), aB[3]*SV1*bfhi(gpkB[2*t+1])); }
            }
        }
        WSYNC();   // writes done before fragment reads
#pragma unroll
        for (int kt = 0; kt < 4; kt++) {
            vfA[c][kt] = LDSR(rlinA + kt * 64);
            vfB[c][kt] = LDSR(rlinB + kt * 64);
        }
        WSYNC();   // reads landed before next channel overwrites the slot
    }
#pragma unroll 1
    for (int t = 0; t < 8; t++) {
        f32x4 c0A={0.f,0.f,0.f,0.f}, c1A={0.f,0.f,0.f,0.f}, c2A={0.f,0.f,0.f,0.f};
        f32x4 c0B={0.f,0.f,0.f,0.f}, c1B={0.f,0.f,0.f,0.f}, c2B={0.f,0.f,0.f,0.f};
#pragma unroll
        for (int kt = 0; kt < 4; kt++) {
            short8 w = pw2v1[(kt * 8 + t) * 64 + lane];
            c0A = MFMA(w, vfA[0][kt], c0A);
            c1A = MFMA(w, vfA[1][kt], c1A);
            c2A = MFMA(w, vfA[2][kt], c2A);
            c0B = MFMA(w, vfB[0][kt], c0B);
            c1B = MFMA(w, vfB[1][kt], c1B);
            c2B = MFMA(w, vfB[2][kt], c2B);
        }
        int base = 256 + 3 * (t * 16 + q * 4);
        {
            fv4 r0 = NTL(xrowA + base), r1 = NTL(xrowA + base + 4), r2 = NTL(xrowA + base + 8);
            fv4 o0 = {r0[0]+c0A[0]*SV1, r0[1]+c1A[0]*SV1, r0[2]+c2A[0]*SV1, r0[3]+c0A[1]*SV1};
            fv4 o1 = {r1[0]+c1A[1]*SV1, r1[1]+c2A[1]*SV1, r1[2]+c0A[2]*SV1, r1[3]+c1A[2]*SV1};
            fv4 o2 = {r2[0]+c2A[2]*SV1, r2[1]+c0A[3]*SV1, r2[2]+c1A[3]*SV1, r2[3]+c2A[3]*SV1};
            STS(yrowA + base, o0); STS(yrowA + base + 4, o1); STS(yrowA + base + 8, o2);
        }
        {
            fv4 r0 = NTL(xrowB + base), r1 = NTL(xrowB + base + 4), r2 = NTL(xrowB + base + 8);
            fv4 o0 = {r0[0]+c0B[0]*SV1, r0[1]+c1B[0]*SV1, r0[2]+c2B[0]*SV1, r0[3]+c0B[1]*SV1};
            fv4 o1 = {r1[0]+c1B[1]*SV1, r1[1]+c2B[1]*SV1, r1[2]+c0B[2]*SV1, r1[3]+c1B[2]*SV1};
            fv4 o2 = {r2[0]+c2B[2]*SV1, r2[1]+c0B[3]*SV1, r2[2]+c1B[3]*SV1, r2[3]+c2B[3]*SV1};
            STS(yrowB + base, o0); STS(yrowB + base + 4, o1); STS(yrowB + base + 8, o2);
        }
    }

    // ---- phase 4: v2 (5 channels) — x loaded once, channels streamed via LDS slot ----
    short8 xf2A[5][2], xf2B[5][2];
#pragma unroll
    for (int kt = 0; kt < 2; kt++) {
        float bA[40], bB[40];
        const float* pA = xrowA + 640 + 5 * (kt * 32 + q * 8);
        const float* pB = xrowB + 640 + 5 * (kt * 32 + q * 8);
#pragma unroll
        for (int i = 0; i < 10; i++) {
            *(fv4*)(bA + 4 * i) = *(const fv4*)(pA + 4 * i);
            *(fv4*)(bB + 4 * i) = *(const fv4*)(pB + 4 * i);
        }
#pragma unroll
        for (int c = 0; c < 5; c++) {
            xf2A[c][kt] = mk8(pk2(bA[c], bA[c+5]), pk2(bA[c+10], bA[c+15]),
                              pk2(bA[c+20], bA[c+25]), pk2(bA[c+30], bA[c+35]));
            xf2B[c][kt] = mk8(pk2(bB[c], bB[c+5]), pk2(bB[c+10], bB[c+15]),
                              pk2(bB[c+20], bB[c+25]), pk2(bB[c+30], bB[c+35]));
        }
    }
    short8 vf2A[5][2], vf2B[5][2];
#pragma unroll
    for (int c = 0; c < 5; c++) {
#pragma unroll
        for (int tp = 0; tp < 2; tp++) {
            f32x4 a0A = {0.f,0.f,0.f,0.f}, a1A = {0.f,0.f,0.f,0.f};
            f32x4 a0B = {0.f,0.f,0.f,0.f}, a1B = {0.f,0.f,0.f,0.f};
#pragma unroll
            for (int kt = 0; kt < 2; kt++) {
                short8 w0 = pw1v2[(kt * 4 + 2 * tp + 0) * 64 + lane];
                short8 w1 = pw1v2[(kt * 4 + 2 * tp + 1) * 64 + lane];
                a0A = MFMA(w0, xf2A[c][kt], a0A);
                a0B = MFMA(w0, xf2B[c][kt], a0B);
                a1A = MFMA(w1, xf2A[c][kt], a1A);
                a1B = MFMA(w1, xf2B[c][kt], a1B);
            }
#pragma unroll
            for (int h = 0; h < 2; h++) {
                f32x4 aA = h ? a1A : a0A, aB = h ? a1B : a0B;
                int t = 2 * tp + h;
                { unsigned i = ((unsigned)(wlinA + t * 8)) ^ swzd;
                  Sd[i]     = pk2(aA[0]*SV2*bflo(gpkA[16+2*t]),   aA[1]*SV2*bfhi(gpkA[16+2*t]));
                  Sd[i + 1] = pk2(aA[2]*SV2*bflo(gpkA[16+2*t+1]), aA[3]*SV2*bfhi(gpkA[16+2*t+1])); }
                { unsigned i = ((unsigned)(wlinB + t * 8)) ^ swzd;
                  Sd[i]     = pk2(aB[0]*SV2*bflo(gpkB[16+2*t]),   aB[1]*SV2*bfhi(gpkB[16+2*t]));
                  Sd[i + 1] = pk2(aB[2]*SV2*bflo(gpkB[16+2*t+1]), aB[3]*SV2*bfhi(gpkB[16+2*t+1])); }
            }
        }
        WSYNC();
#pragma unroll
        for (int kt = 0; kt < 2; kt++) {
            vf2A[c][kt] = LDSR(rlinA + kt * 64);
            vf2B[c][kt] = LDSR(rlinB + kt * 64);
        }
        WSYNC();
    }
#pragma unroll 1
    for (int t = 0; t < 4; t++) {
        f32x4 b0A={0.f,0.f,0.f,0.f}, b1A={0.f,0.f,0.f,0.f}, b2A={0.f,0.f,0.f,0.f},
              b3A={0.f,0.f,0.f,0.f}, b4A={0.f,0.f,0.f,0.f};
        f32x4 b0B={0.f,0.f,0.f,0.f}, b1B={0.f,0.f,0.f,0.f}, b2B={0.f,0.f,0.f,0.f},
              b3B={0.f,0.f,0.f,0.f}, b4B={0.f,0.f,0.f,0.f};
#pragma unroll
        for (int kt = 0; kt < 2; kt++) {
            short8 w = pw2v2[(kt * 4 + t) * 64 + lane];
            b0A = MFMA(w, vf2A[0][kt], b0A);
            b1A = MFMA(w, vf2A[1][kt], b1A);
            b2A = MFMA(w, vf2A[2][kt], b2A);
            b3A = MFMA(w, vf2A[3][kt], b3A);
            b4A = MFMA(w, vf2A[4][kt], b4A);
            b0B = MFMA(w, vf2B[0][kt], b0B);
            b1B = MFMA(w, vf2B[1][kt], b1B);
            b2B = MFMA(w, vf2B[2][kt], b2B);
            b3B = MFMA(w, vf2B[3][kt], b3B);
            b4B = MFMA(w, vf2B[4][kt], b4B);
        }
        int base = 640 + 5 * (t * 16 + q * 4);
        {
            fv4 r0 = NTL(xrowA + base),      r1 = NTL(xrowA + base + 4),
                r2 = NTL(xrowA + base + 8),  r3 = NTL(xrowA + base + 12),
                r4 = NTL(xrowA + base + 16);
            fv4 o0 = {r0[0]+b0A[0]*SV2, r0[1]+b1A[0]*SV2, r0[2]+b2A[0]*SV2, r0[3]+b3A[0]*SV2};
            fv4 o1 = {r1[0]+b4A[0]*SV2, r1[1]+b0A[1]*SV2, r1[2]+b1A[1]*SV2, r1[3]+b2A[1]*SV2};
            fv4 o2 = {r2[0]+b3A[1]*SV2, r2[1]+b4A[1]*SV2, r2[2]+b0A[2]*SV2, r2[3]+b1A[2]*SV2};
            fv4 o3 = {r3[0]+b2A[2]*SV2, r3[1]+b3A[2]*SV2, r3[2]+b4A[2]*SV2, r3[3]+b0A[3]*SV2};
            fv4 o4 = {r4[0]+b1A[3]*SV2, r4[1]+b2A[3]*SV2, r4[2]+b3A[3]*SV2, r4[3]+b4A[3]*SV2};
            STS(yrowA + base, o0); STS(yrowA + base + 4, o1); STS(yrowA + base + 8, o2);
            STS(yrowA + base + 12, o3); STS(yrowA + base + 16, o4);
        }
        {
            fv4 r0 = NTL(xrowB + base),      r1 = NTL(xrowB + base + 4),
                r2 = NTL(xrowB + base + 8),  r3 = NTL(xrowB + base + 12),
                r4 = NTL(xrowB + base + 16);
            fv4 o0 = {r0[0]+b0B[0]*SV2, r0[1]+b1B[0]*SV2, r0[2]+b2B[0]*SV2, r0[3]+b3B[0]*SV2};
            fv4 o1 = {r1[0]+b4B[0]*SV2, r1[1]+b0B[1]*SV2, r1[2]+b1B[1]*SV2, r1[3]+b2B[1]*SV2};
            fv4 o2 = {r2[0]+b3B[1]*SV2, r2[1]+b4B[1]*SV2, r2[2]+b0B[2]*SV2, r2[3]+b1B[2]*SV2};
            fv4 o3 = {r3[0]+b2B[2]*SV2, r3[1]+b3B[2]*SV2, r3[2]+b4B[2]*SV2, r3[3]+b0B[3]*SV2};
            fv4 o4 = {r4[0]+b1B[3]*SV2, r4[1]+b2B[3]*SV2, r4[2]+b3B[3]*SV2, r4[3]+b4B[3]*SV2};
            STS(yrowB + base, o0); STS(yrowB + base + 4, o1); STS(yrowB + base + 8, o2);
            STS(yrowB + base + 12, o3); STS(yrowB + base + 16, o4);
        }
    }
#undef LDSR
}

static float compute_cssp() {
    const int N = 200001;
    const double dz = 20.0 / 200000.0;
    double sum = 0.0;
    for (int i = 0; i < N; i++) {
        double z = -10.0 + dz * i;
        double f = (z > 0 ? z : 0.0) + log1p(exp(-fabs(z))) - 0.69314718055994530942;
        double phi = exp(-0.5 * z * z) * 0.39894228040143267794;
        double y = f * f * phi;
        sum += (i == 0 || i == N - 1) ? 0.5 * y : y;
    }
    return (float)(1.0 / sqrt(sum * dz));
}

extern "C" void kernel_launch(void* const* d_in, const int* in_sizes, int n_in,
                              void* d_out, int out_size, void* d_ws, size_t ws_size,
                              hipStream_t stream) {
    const float* x    = (const float*)d_in[0];
    const float* w1s  = (const float*)d_in[1];
    const float* w1v1 = (const float*)d_in[2];
    const float* w1v2 = (const float*)d_in[3];
    const float* w2s  = (const float*)d_in[4];
    const float* w2v1 = (const float*)d_in[5];
    const float* w2v2 = (const float*)d_in[6];
    float* out = (float*)d_out;

    static const float c_ssp = compute_cssp();

    int rows = in_sizes[0] / XP;
    int blocks = rows / 128;

    pack_weights<<<108, 256, 0, stream>>>(w1s, w1v1, w1v2, w2s, w2v1, w2v2);
    fused_kernel<<<blocks, 256, 0, stream>>>(x, out, c_ssp);
}